// Round 13
// baseline (220.415 us; speedup 1.0000x reference)
//
#include <hip/hip_runtime.h>
#include <math.h>

// EquivariantWSSHead: V=100000 vertices, E=1600000 edges, C0=C1=16.
//
// R1..R4: global-atomic designs floored ~70us/pass; binning+fusion 202us.
// R5/R6/R8: ext_vector kernel params, nontemporal builtins, 57KB LDS stage
//   + register payload arrays crash the container. Keep constructs bland.
// R7/R9/R10: randomness must die in LDS (R9 random writes W55; R10 random
//   reads F127).
// R11: LDS tuple-sort scatter (seq reads+writes). 181us.
// R12: VB=256 line-sized runs: bucket FETCH 33->23MB but dur 49->48us —
//   traffic was NOT the bottleneck. ALL kernels sit at 40-48us while
//   modeled in-kernel work is ~5-15us each => suspect large fixed
//   per-dispatch cost (graph node boundaries) or shared hidden cost.
//   Also: precompute LDS stride 48 floats = 32-way bank conflict.
// R13: ONE kernel, 256 blocks x 1024 threads, manual grid barriers:
//   - co-residency guaranteed: 52KB LDS -> >=1 block/CU, 256 blocks.
//   - __threadfence() + device atomics = release/acquire across XCDs.
//   - barrier counters zeroed by 16B hipMemsetAsync before launch.
//   - phase A: precompute table (LDS row stride 49 -> conflict-free).
//   - phase B: 2 sub-chunks of R12's tuple-sort scatter per block.
//   - phase C: buckets strided over blocks; runs split front/back.
//
// Math: per-edge work factors through per-src-vertex dot products:
//   u1.w = cg*(a.w) - sg*(b.w),  u2.w = sg*(a.w) + cg*(b.w)
// so phase A makes a 16-bf16 (32B) table line per vertex (3.2MB).

#define VB 256           // vertices per bucket
#define VB_SHIFT 8
#define BLOCKS 256
#define BIGT 1024
#define MAXNB 400        // NB = ceil(V/256) = 391 for V=100000
#define CHUNK 3125       // edges per sub-chunk
#define CHUNKP 3136      // padded entries (8B) -> 64B-aligned regions
#define SUBC 2           // sub-chunks per block (nblk = BLOCKS*SUBC = 512)

typedef unsigned int uint32;

static __device__ __forceinline__ uint32 f2bf(float f) {
    uint32 u = __float_as_uint(f);
    return (u + 0x7FFFu + ((u >> 16) & 1u)) >> 16;   // RNE to bf16
}
static __device__ __forceinline__ uint32 pack2(float lo, float hi) {
    return f2bf(lo) | (f2bf(hi) << 16);
}
static __device__ __forceinline__ float bf_lo(uint32 u) {
    return __uint_as_float(u << 16);
}
static __device__ __forceinline__ float bf_hi(uint32 u) {
    return __uint_as_float(u & 0xFFFF0000u);
}

// Grid barrier: all BLOCKS blocks arrive at slot, spin until full.
// __threadfence = agent-scope fence (L2 writeback+invalidate on gfx9xx)
// so non-atomic data written before the barrier is visible after it.
static __device__ __forceinline__ void grid_barrier(int* bar, int slot) {
    __syncthreads();
    if (threadIdx.x == 0) {
        __threadfence();
        atomicAdd(&bar[slot], 1);
        while (atomicAdd(&bar[slot], 0) < BLOCKS) { }
        __threadfence();
    }
    __syncthreads();
}

__global__ __launch_bounds__(BIGT)
void fused_kernel(const float* __restrict__ x,
                  const int* __restrict__ src,
                  const int* __restrict__ dst,
                  const float* __restrict__ angles,
                  const float* __restrict__ transporters,
                  const float* __restrict__ e1,
                  const float* __restrict__ e2,
                  const float* __restrict__ w_self0,
                  const float* __restrict__ w_n00,
                  const float* __restrict__ w_n10,
                  const float* __restrict__ w_self11,
                  const float* __restrict__ w_n01,
                  const float* __restrict__ w_n11,
                  int* __restrict__ bar,
                  int* __restrict__ runmat,
                  uint32* __restrict__ table,
                  float* __restrict__ selfbuf,
                  uint2* __restrict__ payload,
                  float* __restrict__ out,
                  int V, int E, int NB, int nblk) {
    __shared__ __align__(16) char smem[53248];   // 52KB union
    int tid = threadIdx.x;
    int b = blockIdx.x;

    // ---------------- phase A: per-vertex dot-product table ----------------
    {
        float* stage = (float*)smem;             // 256 rows x 49 floats
        int RPB = (V + BLOCKS - 1) / BLOCKS;     // 391
        int rowbase = b * RPB;
        for (int t0 = 0; t0 < RPB; t0 += 256) {
            int v0 = rowbase + t0;
            int nv = min(256, min(RPB - t0, V - v0));
            __syncthreads();
            if (nv > 0) {
                const float4* x4 = (const float4*)(x + (size_t)v0 * 48);
                int n4 = nv * 12;
                for (int j = tid; j < n4; j += BIGT) {
                    float4 f = x4[j];
                    int r = j / 12, c = (j % 12) * 4;
                    float* dp = stage + r * 49 + c;
                    dp[0] = f.x; dp[1] = f.y; dp[2] = f.z; dp[3] = f.w;
                }
            }
            __syncthreads();
            if (tid < nv) {
                int v = v0 + tid;
                const float* xr = stage + tid * 49;
                float d00 = 0.f, aw0 = 0.f, bw0 = 0.f, aw1 = 0.f, bw1 = 0.f;
                float d01a = 0.f, d01b = 0.f;
                float aP = 0.f, bP = 0.f, aQ = 0.f, bQ = 0.f;
                float aR = 0.f, bR = 0.f, aS = 0.f, bS = 0.f;
                float selfmag = 0.f, t1s = 0.f, t2s = 0.f;
#pragma unroll
                for (int i = 0; i < 16; ++i) {
                    float x0 = xr[i];
                    float a  = xr[16 + 2 * i];
                    float bb = xr[17 + 2 * i];
                    d00     += x0 * w_n00[i];
                    selfmag += x0 * w_self0[i];
                    d01a    += x0 * w_n01[i * 2 + 0];
                    d01b    += x0 * w_n01[i * 2 + 1];
                    float w0 = w_n10[i * 2 + 0], w1 = w_n10[i * 2 + 1];
                    aw0 += a * w0;  bw0 += bb * w0;
                    aw1 += a * w1;  bw1 += bb * w1;
                    float p = w_n11[i * 4 + 0], q = w_n11[i * 4 + 1];
                    float r = w_n11[i * 4 + 2], s = w_n11[i * 4 + 3];
                    aP += a * p;  bP += bb * p;
                    aQ += a * q;  bQ += bb * q;
                    aR += a * r;  bR += bb * r;
                    aS += a * s;  bS += bb * s;
                    float sa_ = w_self11[i * 2 + 0], sb_ = w_self11[i * 2 + 1];
                    t1s += a * sa_ - bb * sb_;
                    t2s += bb * sa_ + a * sb_;
                }
                uint4 w0, w1;
                w0.x = pack2(d00, aw0);  w0.y = pack2(bw0, aw1);
                w0.z = pack2(bw1, d01a); w0.w = pack2(d01b, aP);
                w1.x = pack2(bP, aQ);    w1.y = pack2(bQ, aR);
                w1.z = pack2(bR, aS);    w1.w = pack2(bS, 0.f);
                uint4* tp = (uint4*)(table + (size_t)v * 8);
                tp[0] = w0;  tp[1] = w1;
                float* sf = selfbuf + (size_t)v * 4;
                sf[0] = selfmag; sf[1] = t1s; sf[2] = t2s; sf[3] = 0.f;
            }
        }
    }
    grid_barrier(bar, 0);

    // ---------------- phase B: tuple-sort scatter (2 sub-chunks) -----------
    {
        int* cnt_l   = (int*)smem;               // 400 ints
        int* wsum    = cnt_l + MAXNB;            // 16 ints
        uint32* dstl = (uint32*)(cnt_l + MAXNB + 16);
        uint32* tw0  = dstl + CHUNKP;
        uint32* tw1  = tw0 + CHUNKP;
        uint32* tw2  = tw1 + CHUNKP;
        int lane = tid & 63;
        int wv = tid >> 6;
        for (int s = 0; s < SUBC; ++s) {
            int cb = b * SUBC + s;
            int lo = cb * CHUNK;
            int hi = min(E, lo + CHUNK);
            int nloc = hi - lo;
            __syncthreads();
            for (int i = tid; i < NB; i += BIGT) cnt_l[i] = 0;
            __syncthreads();
            for (int i = tid; i < nloc; i += BIGT) {
                uint32 d = (uint32)dst[lo + i];
                dstl[i] = d;
                atomicAdd(&cnt_l[d >> VB_SHIFT], 1);
            }
            __syncthreads();
            int c = (tid < NB) ? cnt_l[tid] : 0;
            int incl = c;
#pragma unroll
            for (int d = 1; d < 64; d <<= 1) {
                int n = __shfl_up(incl, d);
                if (lane >= d) incl += n;
            }
            if (lane == 63) wsum[wv] = incl;
            __syncthreads();
            if (tid < 16) {
                int wval = wsum[tid], winc = wval;
#pragma unroll
                for (int d = 1; d < 16; d <<= 1) {
                    int n = __shfl_up(winc, d);
                    if (lane >= d) winc += n;
                }
                wsum[tid] = winc - wval;
            }
            __syncthreads();
            int bCH = cb * CHUNKP;
            if (tid < NB) {
                int ex = incl - c + wsum[wv];
                runmat[(size_t)tid * nblk + cb] = bCH + ex;
                cnt_l[tid] = ex;
            }
            if (tid == 0)
                runmat[(size_t)NB * nblk + cb] = bCH + nloc;
            __syncthreads();
            for (int i = tid; i < nloc; i += BIGT) {
                uint32 d = dstl[i];
                int bin = (int)(d >> VB_SHIFT);
                uint32 dl = d & (VB - 1);
                int pos = atomicAdd(&cnt_l[bin], 1);
                tw0[pos] = (uint32)src[lo + i] | (dl << 17);
                tw1[pos] = __float_as_uint(angles[lo + i]);
                tw2[pos] = __float_as_uint(transporters[lo + i]);
            }
            __syncthreads();
            for (int k = tid; k < nloc; k += BIGT) {
                uint32 w0i = tw0[k];
                int sidx = (int)(w0i & 0x1FFFFu);
                int dl   = (int)(w0i >> 17);
                float ang = __uint_as_float(tw1[k]);
                float trv = __uint_as_float(tw2[k]);
                float st, ct, sg, cg;
                sincosf(ang, &st, &ct);
                sincosf(trv, &sg, &cg);
                float c2t = ct * ct - st * st;
                float s2t = 2.0f * st * ct;

                const uint4* tp = (const uint4*)(table + (size_t)sidx * 8);
                uint4 W0 = tp[0], W1 = tp[1];
                float d00 = bf_lo(W0.x), aw0 = bf_hi(W0.x);
                float bw0 = bf_lo(W0.y), aw1 = bf_hi(W0.y);
                float bw1 = bf_lo(W0.z), d01a = bf_hi(W0.z);
                float d01b = bf_lo(W0.w), aP = bf_hi(W0.w);
                float bP = bf_lo(W1.x), aQ = bf_hi(W1.x);
                float bQ = bf_lo(W1.y), aR = bf_hi(W1.y);
                float bR = bf_lo(W1.z), aS = bf_hi(W1.z);
                float bS = bf_lo(W1.w);

                float u1w0 = cg * aw0 - sg * bw0, u2w0 = sg * aw0 + cg * bw0;
                float u1w1 = cg * aw1 - sg * bw1, u2w1 = sg * aw1 + cg * bw1;
                float m0 = d00 + ct * u1w0 + st * u2w0 - st * u1w1 + ct * u2w1;

                float u1p = cg * aP - sg * bP, u2p = sg * aP + cg * bP;
                float u1q = cg * aQ - sg * bQ, u2q = sg * aQ + cg * bQ;
                float u1r = cg * aR - sg * bR, u2r = sg * aR + cg * bR;
                float u1s = cg * aS - sg * bS, u2s = sg * aS + cg * bS;

                float mv1 = d01a * ct - d01b * st
                          + u1p - u2q
                          + c2t * u1r + s2t * u2r
                          - (s2t * u1s - c2t * u2s);
                float mv2 = d01a * st + d01b * ct
                          + u2p + u1q
                          + s2t * u1r - c2t * u2r
                          + c2t * u1s + s2t * u2s;

                uint2 pl;
                pl.x = pack2(m0, mv1);
                pl.y = f2bf(mv2) | ((uint32)dl << 16);
                payload[bCH + k] = pl;
            }
        }
    }
    grid_barrier(bar, 1);

    // ---------------- phase C: bucket reduce + finalize --------------------
    {
        float* acc = (float*)smem;               // 8 copies x 256 x 4 = 32KB
        float* myacc = acc + (size_t)(tid >> 7) * (VB * 4);
        int t = tid & 511;
        int halfsel = tid >> 9;
        for (int bin = b; bin < NB; bin += BLOCKS) {
            __syncthreads();
            for (int i = tid; i < 8 * VB * 4; i += BIGT) acc[i] = 0.f;
            __syncthreads();
            if (t < nblk) {
                int st = runmat[(size_t)bin * nblk + t];
                int en = runmat[(size_t)(bin + 1) * nblk + t];
                int len = en - st;
                int h = (len + 1) >> 1;
                int k0 = halfsel ? st + h : st;
                int k1 = halfsel ? en : st + h;
                for (int k = k0; k < k1; ++k) {
                    uint2 pl = payload[k];
                    float m0  = bf_lo(pl.x);
                    float mv1 = bf_hi(pl.x);
                    float mv2 = bf_lo(pl.y);
                    int dl = (int)(pl.y >> 16);
                    atomicAdd(&myacc[dl * 4 + 0], m0);
                    atomicAdd(&myacc[dl * 4 + 1], mv1);
                    atomicAdd(&myacc[dl * 4 + 2], mv2);
                    atomicAdd(&myacc[dl * 4 + 3], 1.0f);
                }
            }
            __syncthreads();
            if (tid < VB) {
                int v = bin * VB + tid;
                if (v < V) {
                    float A0 = 0.f, A1 = 0.f, A2 = 0.f, A3 = 0.f;
#pragma unroll
                    for (int w = 0; w < 8; ++w) {
                        A0 += acc[w * VB * 4 + tid * 4 + 0];
                        A1 += acc[w * VB * 4 + tid * 4 + 1];
                        A2 += acc[w * VB * 4 + tid * 4 + 2];
                        A3 += acc[w * VB * 4 + tid * 4 + 3];
                    }
                    float inv = 1.0f / fmaxf(A3, 1.0f);
                    const float* sf = selfbuf + (size_t)v * 4;
                    float mag = A0 * inv + sf[0];
                    float t1  = A1 * inv + sf[1];
                    float t2  = A2 * inv + sf[2];
                    float scale = 2.0f / (1.0f + expf(-mag));
                    float e1x = e1[v * 3 + 0], e1y = e1[v * 3 + 1];
                    float e1z = e1[v * 3 + 2];
                    float e2x = e2[v * 3 + 0], e2y = e2[v * 3 + 1];
                    float e2z = e2[v * 3 + 2];
                    out[v * 3 + 0] = (t1 * e1x + t2 * e2x) * scale;
                    out[v * 3 + 1] = (t1 * e1y + t2 * e2y) * scale;
                    out[v * 3 + 2] = (t1 * e1z + t2 * e2z) * scale;
                }
            }
        }
    }
}

extern "C" void kernel_launch(void* const* d_in, const int* in_sizes, int n_in,
                              void* d_out, int out_size, void* d_ws, size_t ws_size,
                              hipStream_t stream) {
    const float* x            = (const float*)d_in[0];
    const int*   edge_index   = (const int*)d_in[1];
    const float* angles       = (const float*)d_in[2];
    const float* transporters = (const float*)d_in[3];
    const float* e1           = (const float*)d_in[4];
    const float* e2           = (const float*)d_in[5];
    const float* w_self0      = (const float*)d_in[6];
    const float* w_n00        = (const float*)d_in[7];
    const float* w_n10        = (const float*)d_in[8];
    const float* w_self11     = (const float*)d_in[9];
    const float* w_n01        = (const float*)d_in[10];
    const float* w_n11        = (const float*)d_in[11];
    float* out = (float*)d_out;

    int V = in_sizes[0] / 48;
    int E = in_sizes[2];
    const int* src = edge_index;
    const int* dst = edge_index + E;

    int NB = (V + VB - 1) / VB;          // 391 for V=100000
    int nblk = BLOCKS * SUBC;            // 512

    char* p = (char*)d_ws;
    int* bar = (int*)p;           p += 64;
    int* runmat = (int*)p;        p += (size_t)(NB + 1) * nblk * 4;
    uint32* table  = (uint32*)p;  p += (size_t)V * 8 * 4;
    float* selfbuf = (float*)p;   p += (size_t)V * 4 * 4;
    p = (char*)(((uintptr_t)p + 63) & ~(uintptr_t)63);
    uint2* payload = (uint2*)p;   // nblk * CHUNKP * 8 bytes (~12.9 MB)

    hipMemsetAsync(bar, 0, 64, stream);
    fused_kernel<<<BLOCKS, BIGT, 0, stream>>>(x, src, dst, angles,
                                              transporters, e1, e2,
                                              w_self0, w_n00, w_n10,
                                              w_self11, w_n01, w_n11,
                                              bar, runmat, table, selfbuf,
                                              payload, out, V, E, NB, nblk);
}

// Round 14
// 184.875 us; speedup vs baseline: 1.1922x; 1.1922x over previous
//
#include <hip/hip_runtime.h>
#include <math.h>

// EquivariantWSSHead: V=100000 vertices, E=1600000 edges, C0=C1=16.
//
// R1..R12 summary: zero-global-atomic bucket binning; bf16 table (3.2MB) +
//   8B payload; LDS tuple-sort so scatter reads AND writes are sequential.
//   Best 177us. Container crashers to avoid: ext_vector kernel params,
//   nontemporal builtins, 57KB LDS + register payload arrays.
// R13 (fused, grid barriers): 147us in ONE kernel => per-kernel time was
//   real; dur_us has a fixed ~70us harness floor. Fusion regressed; revert.
// R12 bucket diagnosis: reads = 512 unique 64B lines/block scattered over
//   12.9MB (threads 25KB apart) -> MSHR/latency-capped at ~520GB/s. Fix:
//   make each bin's payload CONTIGUOUS.
// R14: bin-major line-aligned payload, written directly by scatter:
//   K2 count:    per-chunk histogram -> cntmat[bin][chunk]
//   K3 padscan:  per-bin padded (8-entry aligned) prefix over chunks ->
//                padprefT[chunk][bin] + padtotal[bin]
//   K4 binbase:  exclusive scan of padtotal -> binpadbase
//   K5 scatter:  local LDS tuple-sort (R12) + write runs at
//                binpadbase[bin]+padprefT[b][bin] (line-aligned, 1 writer)
//   K6 bucket:   per-bin CONTIGUOUS stream read, flat coalesced consume
//                (LDS group2run masks padding), LDS acc, fused finalize
//   Precompute LDS row stride 48->49 (was a 32-way bank conflict).

#define VB 256           // vertices per bucket
#define VB_SHIFT 8
#define MAXNB 400        // NB = ceil(V/256) = 391 for V=100000
#define CHUNK 3125       // edges per chunk
#define NCHUNK 512       // chunks (E/CHUNK)
#define BIGT 1024

typedef unsigned int uint32;

static __device__ __forceinline__ uint32 f2bf(float f) {
    uint32 u = __float_as_uint(f);
    return (u + 0x7FFFu + ((u >> 16) & 1u)) >> 16;   // RNE to bf16
}
static __device__ __forceinline__ uint32 pack2(float lo, float hi) {
    return f2bf(lo) | (f2bf(hi) << 16);
}
static __device__ __forceinline__ float bf_lo(uint32 u) {
    return __uint_as_float(u << 16);
}
static __device__ __forceinline__ float bf_hi(uint32 u) {
    return __uint_as_float(u & 0xFFFF0000u);
}

// K1: per-vertex dot-product table. 256 rows staged in LDS, row stride 49
// floats (odd -> 2-way bank alias only, free). All 256 threads compute.
__global__ __launch_bounds__(256)
void precompute_kernel(const float* __restrict__ x,
                       const float* __restrict__ w_self0,
                       const float* __restrict__ w_n00,
                       const float* __restrict__ w_n10,
                       const float* __restrict__ w_self11,
                       const float* __restrict__ w_n01,
                       const float* __restrict__ w_n11,
                       uint32* __restrict__ table,   // 8 u32/vertex
                       float* __restrict__ selfbuf,
                       int V) {
    __shared__ float stage[256 * 49];   // 50KB
    int v0 = blockIdx.x * 256;
    int nv = min(256, V - v0);
    if (nv <= 0) return;
    int tid = threadIdx.x;
    {
        const float4* x4 = (const float4*)(x + (size_t)v0 * 48);
        int n4 = nv * 12;
        for (int j = tid; j < n4; j += 256) {
            float4 f = x4[j];
            float* dp = stage + (j / 12) * 49 + (j % 12) * 4;
            dp[0] = f.x; dp[1] = f.y; dp[2] = f.z; dp[3] = f.w;
        }
    }
    __syncthreads();
    if (tid >= nv) return;
    int v = v0 + tid;
    const float* xr = stage + tid * 49;
    float d00 = 0.f, aw0 = 0.f, bw0 = 0.f, aw1 = 0.f, bw1 = 0.f;
    float d01a = 0.f, d01b = 0.f;
    float aP = 0.f, bP = 0.f, aQ = 0.f, bQ = 0.f;
    float aR = 0.f, bR = 0.f, aS = 0.f, bS = 0.f;
    float selfmag = 0.f, t1s = 0.f, t2s = 0.f;
#pragma unroll
    for (int i = 0; i < 16; ++i) {
        float x0 = xr[i];
        float a  = xr[16 + 2 * i];
        float b  = xr[17 + 2 * i];
        d00     += x0 * w_n00[i];
        selfmag += x0 * w_self0[i];
        d01a    += x0 * w_n01[i * 2 + 0];
        d01b    += x0 * w_n01[i * 2 + 1];
        float w0 = w_n10[i * 2 + 0], w1 = w_n10[i * 2 + 1];
        aw0 += a * w0;  bw0 += b * w0;
        aw1 += a * w1;  bw1 += b * w1;
        float p = w_n11[i * 4 + 0], q = w_n11[i * 4 + 1];
        float r = w_n11[i * 4 + 2], s = w_n11[i * 4 + 3];
        aP += a * p;  bP += b * p;
        aQ += a * q;  bQ += b * q;
        aR += a * r;  bR += b * r;
        aS += a * s;  bS += b * s;
        float sa_ = w_self11[i * 2 + 0], sb_ = w_self11[i * 2 + 1];
        t1s += a * sa_ - b * sb_;
        t2s += b * sa_ + a * sb_;
    }
    uint4 w0, w1;
    w0.x = pack2(d00, aw0);  w0.y = pack2(bw0, aw1);
    w0.z = pack2(bw1, d01a); w0.w = pack2(d01b, aP);
    w1.x = pack2(bP, aQ);    w1.y = pack2(bQ, aR);
    w1.z = pack2(bR, aS);    w1.w = pack2(bS, 0.f);
    uint4* tp = (uint4*)(table + (size_t)v * 8);
    tp[0] = w0;  tp[1] = w1;
    float* sf = selfbuf + (size_t)v * 4;
    sf[0] = selfmag; sf[1] = t1s; sf[2] = t2s; sf[3] = 0.f;
}

// K2: per-chunk histogram -> cntmat[bin][chunk] (stride NCHUNK).
__global__ __launch_bounds__(512)
void count_kernel(const int* __restrict__ dst,
                  int* __restrict__ cntmat,
                  int E, int NB) {
    __shared__ int hist[MAXNB];
    int b = blockIdx.x;
    int lo = b * CHUNK;
    int hi = min(E, lo + CHUNK);
    for (int i = threadIdx.x; i < NB; i += 512) hist[i] = 0;
    __syncthreads();
    for (int e = lo + threadIdx.x; e < hi; e += 512)
        atomicAdd(&hist[dst[e] >> VB_SHIFT], 1);
    __syncthreads();
    for (int i = threadIdx.x; i < NB; i += 512)
        cntmat[(size_t)i * NCHUNK + b] = hist[i];
}

// K3: one wave per bin. Padded (8-aligned) exclusive prefix over the 512
// chunk counts -> padprefT[chunk][bin] (stride MAXNB); padtotal[bin].
__global__ __launch_bounds__(256)
void padscan_kernel(const int* __restrict__ cntmat,
                    int* __restrict__ padprefT,
                    int* __restrict__ padtotal,
                    int NB) {
    int lane = threadIdx.x & 63;
    int wv = threadIdx.x >> 6;
    int bin = blockIdx.x * 4 + wv;
    if (bin >= NB) return;
    const int* row = cntmat + (size_t)bin * NCHUNK;
    int c[8], p[8];
#pragma unroll
    for (int j = 0; j < 8; ++j) {
        c[j] = row[lane * 8 + j];
        p[j] = (c[j] + 7) & ~7;
    }
    int e[8];
    int run = 0;
#pragma unroll
    for (int j = 0; j < 8; ++j) { e[j] = run; run += p[j]; }
    int T = run;
    int incl = T;
#pragma unroll
    for (int d = 1; d < 64; d <<= 1) {
        int n = __shfl_up(incl, d);
        if (lane >= d) incl += n;
    }
    int base = incl - T;
#pragma unroll
    for (int j = 0; j < 8; ++j)
        padprefT[(size_t)(lane * 8 + j) * MAXNB + bin] = base + e[j];
    if (lane == 63) padtotal[bin] = incl;
}

// K4: exclusive scan of padtotal -> binpadbase[0..NB].
__global__ __launch_bounds__(512)
void binbase_kernel(const int* __restrict__ padtotal,
                    int* __restrict__ binpadbase,
                    int NB) {
    __shared__ int wsum[8];
    int t = threadIdx.x;
    int lane = t & 63;
    int wv = t >> 6;
    int val = (t < NB) ? padtotal[t] : 0;
    int incl = val;
#pragma unroll
    for (int d = 1; d < 64; d <<= 1) {
        int n = __shfl_up(incl, d);
        if (lane >= d) incl += n;
    }
    if (lane == 63) wsum[wv] = incl;
    __syncthreads();
    if (t < 8) {
        int wval = wsum[t], winc = wval;
#pragma unroll
        for (int d = 1; d < 8; d <<= 1) {
            int n = __shfl_up(winc, d);
            if (lane >= d) winc += n;
        }
        wsum[t] = winc - wval;
    }
    __syncthreads();
    int ex = incl - val + wsum[wv];
    if (t < NB) binpadbase[t] = ex;
    if (t == NB - 1) binpadbase[NB] = ex + val;
}

// K5: local LDS tuple-sort + compute + write into bin-major line-aligned
// runs at binpadbase[bin] + padprefT[chunk][bin].
__global__ __launch_bounds__(BIGT)
void scatter_kernel(const int* __restrict__ src,
                    const int* __restrict__ dst,
                    const float* __restrict__ angles,
                    const float* __restrict__ transporters,
                    const uint32* __restrict__ table,
                    const int* __restrict__ padprefT,
                    const int* __restrict__ binpadbase,
                    uint2* __restrict__ payload,
                    int E, int NB) {
    __shared__ int cnt_l[MAXNB];
    __shared__ int exoff_l[MAXNB];
    __shared__ int slot_l[MAXNB];
    __shared__ int wsum[16];
    __shared__ uint32 tw_src[CHUNK];
    __shared__ uint32 tw_ang[CHUNK];
    __shared__ uint32 tw_tr[CHUNK];
    __shared__ unsigned short tw_bin[CHUNK];

    int b = blockIdx.x;
    int lo = b * CHUNK;
    int hi = min(E, lo + CHUNK);
    int nloc = hi - lo;
    int tid = threadIdx.x;
    int lane = tid & 63;
    int wv = tid >> 6;

    for (int i = tid; i < NB; i += BIGT) cnt_l[i] = 0;
    __syncthreads();

    // pass1: histogram (dst stays L1/L2-warm for pass1b)
    for (int e = lo + tid; e < hi; e += BIGT)
        atomicAdd(&cnt_l[dst[e] >> VB_SHIFT], 1);
    __syncthreads();

    // local exclusive scan over NB counts (shfl two-level)
    int c = (tid < NB) ? cnt_l[tid] : 0;
    int incl = c;
#pragma unroll
    for (int d = 1; d < 64; d <<= 1) {
        int n = __shfl_up(incl, d);
        if (lane >= d) incl += n;
    }
    if (lane == 63) wsum[wv] = incl;
    __syncthreads();
    if (tid < 16) {
        int wval = wsum[tid], winc = wval;
#pragma unroll
        for (int d = 1; d < 16; d <<= 1) {
            int n = __shfl_up(winc, d);
            if (lane >= d) winc += n;
        }
        wsum[tid] = winc - wval;
    }
    __syncthreads();
    if (tid < NB) {
        int ex = incl - c + wsum[wv];
        exoff_l[tid] = ex;
        cnt_l[tid] = ex;                         // cursor
        slot_l[tid] = binpadbase[tid] + padprefT[(size_t)b * MAXNB + tid];
    }
    __syncthreads();

    // pass1b: coalesced reads; tuple -> bin-sorted LDS slot
    for (int e = lo + tid; e < hi; e += BIGT) {
        int d = dst[e];
        int bin = d >> VB_SHIFT;
        uint32 dl = (uint32)(d & (VB - 1));
        int pos = atomicAdd(&cnt_l[bin], 1);
        tw_src[pos] = (uint32)src[e] | (dl << 17);
        tw_ang[pos] = __float_as_uint(angles[e]);
        tw_tr[pos]  = __float_as_uint(transporters[e]);
        tw_bin[pos] = (unsigned short)bin;
    }
    __syncthreads();

    // pass2: compute in bin order, write line-aligned bin-major runs
    for (int k = tid; k < nloc; k += BIGT) {
        int bin = (int)tw_bin[k];
        uint32 w0i = tw_src[k];
        int s  = (int)(w0i & 0x1FFFFu);
        int dl = (int)(w0i >> 17);
        float ang = __uint_as_float(tw_ang[k]);
        float trv = __uint_as_float(tw_tr[k]);
        float st, ct, sg, cg;
        sincosf(ang, &st, &ct);
        sincosf(trv, &sg, &cg);
        float c2t = ct * ct - st * st;
        float s2t = 2.0f * st * ct;

        const uint4* tp = (const uint4*)(table + (size_t)s * 8);
        uint4 W0 = tp[0], W1 = tp[1];
        float d00 = bf_lo(W0.x), aw0 = bf_hi(W0.x);
        float bw0 = bf_lo(W0.y), aw1 = bf_hi(W0.y);
        float bw1 = bf_lo(W0.z), d01a = bf_hi(W0.z);
        float d01b = bf_lo(W0.w), aP = bf_hi(W0.w);
        float bP = bf_lo(W1.x), aQ = bf_hi(W1.x);
        float bQ = bf_lo(W1.y), aR = bf_hi(W1.y);
        float bR = bf_lo(W1.z), aS = bf_hi(W1.z);
        float bS = bf_lo(W1.w);

        float u1w0 = cg * aw0 - sg * bw0, u2w0 = sg * aw0 + cg * bw0;
        float u1w1 = cg * aw1 - sg * bw1, u2w1 = sg * aw1 + cg * bw1;
        float m0 = d00 + ct * u1w0 + st * u2w0 - st * u1w1 + ct * u2w1;

        float u1p = cg * aP - sg * bP, u2p = sg * aP + cg * bP;
        float u1q = cg * aQ - sg * bQ, u2q = sg * aQ + cg * bQ;
        float u1r = cg * aR - sg * bR, u2r = sg * aR + cg * bR;
        float u1s = cg * aS - sg * bS, u2s = sg * aS + cg * bS;

        float mv1 = d01a * ct - d01b * st
                  + u1p - u2q
                  + c2t * u1r + s2t * u2r
                  - (s2t * u1s - c2t * u2s);
        float mv2 = d01a * st + d01b * ct
                  + u2p + u1q
                  + s2t * u1r - c2t * u2r
                  + c2t * u1s + s2t * u2s;

        uint2 pl;
        pl.x = pack2(m0, mv1);
        pl.y = f2bf(mv2) | ((uint32)dl << 16);
        payload[slot_l[bin] + (k - exoff_l[bin])] = pl;
    }
}

// K6: one block per bin. CONTIGUOUS stream read of the bin's padded region;
// flat coalesced consume with LDS group->run masking; LDS acc; finalize.
__global__ __launch_bounds__(BIGT)
void bucket_kernel(const uint2* __restrict__ payload,
                   const int* __restrict__ cntmat,
                   const int* __restrict__ binpadbase,
                   const float* __restrict__ selfbuf,
                   const float* __restrict__ e1,
                   const float* __restrict__ e2,
                   float* __restrict__ out,
                   int V, int NB) {
    __shared__ float acc[8][VB * 4];     // 32KB, wave w uses copy w>>1
    __shared__ int len_l[NCHUNK];
    __shared__ int pstart_l[NCHUNK];
    __shared__ unsigned short group2run[2048];
    int bin = blockIdx.x;
    int tid = threadIdx.x;
    for (int i = tid; i < 8 * VB * 4; i += BIGT) ((float*)acc)[i] = 0.f;

    // read the bin's 512 chunk counts; padded Hillis scan
    if (tid < NCHUNK) {
        int len = cntmat[(size_t)bin * NCHUNK + tid];
        len_l[tid] = len;
        pstart_l[tid] = (len + 7) & ~7;
    }
    __syncthreads();
    for (int stp = 1; stp < NCHUNK; stp <<= 1) {
        int vv = 0;
        if (tid < NCHUNK && tid >= stp) vv = pstart_l[tid - stp];
        __syncthreads();
        if (tid < NCHUNK) pstart_l[tid] += vv;
        __syncthreads();
    }
    // pstart now inclusive; convert to exclusive start + fill group2run
    if (tid < NCHUNK) {
        int plen = (len_l[tid] + 7) & ~7;
        int ps = pstart_l[tid] - plen;
        pstart_l[tid] = ps;
        int g0 = ps >> 3, gn = plen >> 3;
        for (int j = 0; j < gn; ++j)
            group2run[g0 + j] = (unsigned short)tid;
    }
    __syncthreads();

    int base = binpadbase[bin];
    int ptot = binpadbase[bin + 1] - base;
    float* myacc = acc[tid >> 7];
    for (int k = tid; k < ptot; k += BIGT) {
        int r = (int)group2run[k >> 3];
        int local = k - pstart_l[r];
        if (local < len_l[r]) {
            uint2 pl = payload[base + k];
            float m0  = bf_lo(pl.x);
            float mv1 = bf_hi(pl.x);
            float mv2 = bf_lo(pl.y);
            int dl = (int)(pl.y >> 16);
            atomicAdd(&myacc[dl * 4 + 0], m0);
            atomicAdd(&myacc[dl * 4 + 1], mv1);
            atomicAdd(&myacc[dl * 4 + 2], mv2);
            atomicAdd(&myacc[dl * 4 + 3], 1.0f);
        }
    }
    __syncthreads();
    if (tid < VB) {
        int v = bin * VB + tid;
        if (v < V) {
            float A0 = 0.f, A1 = 0.f, A2 = 0.f, A3 = 0.f;
#pragma unroll
            for (int w = 0; w < 8; ++w) {
                A0 += acc[w][tid * 4 + 0];
                A1 += acc[w][tid * 4 + 1];
                A2 += acc[w][tid * 4 + 2];
                A3 += acc[w][tid * 4 + 3];
            }
            float inv = 1.0f / fmaxf(A3, 1.0f);
            const float* sf = selfbuf + (size_t)v * 4;
            float mag = A0 * inv + sf[0];
            float t1  = A1 * inv + sf[1];
            float t2  = A2 * inv + sf[2];
            float scale = 2.0f / (1.0f + expf(-mag));
            float e1x = e1[v * 3 + 0], e1y = e1[v * 3 + 1], e1z = e1[v * 3 + 2];
            float e2x = e2[v * 3 + 0], e2y = e2[v * 3 + 1], e2z = e2[v * 3 + 2];
            out[v * 3 + 0] = (t1 * e1x + t2 * e2x) * scale;
            out[v * 3 + 1] = (t1 * e1y + t2 * e2y) * scale;
            out[v * 3 + 2] = (t1 * e1z + t2 * e2z) * scale;
        }
    }
}

extern "C" void kernel_launch(void* const* d_in, const int* in_sizes, int n_in,
                              void* d_out, int out_size, void* d_ws, size_t ws_size,
                              hipStream_t stream) {
    const float* x            = (const float*)d_in[0];
    const int*   edge_index   = (const int*)d_in[1];
    const float* angles       = (const float*)d_in[2];
    const float* transporters = (const float*)d_in[3];
    const float* e1           = (const float*)d_in[4];
    const float* e2           = (const float*)d_in[5];
    const float* w_self0      = (const float*)d_in[6];
    const float* w_n00        = (const float*)d_in[7];
    const float* w_n10        = (const float*)d_in[8];
    const float* w_self11     = (const float*)d_in[9];
    const float* w_n01        = (const float*)d_in[10];
    const float* w_n11        = (const float*)d_in[11];
    float* out = (float*)d_out;

    int V = in_sizes[0] / 48;
    int E = in_sizes[2];
    const int* src = edge_index;
    const int* dst = edge_index + E;

    int NB = (V + VB - 1) / VB;              // 391
    int nchunk = (E + CHUNK - 1) / CHUNK;    // 512

    char* p = (char*)d_ws;
    int* cntmat     = (int*)p;  p += (size_t)MAXNB * NCHUNK * 4;  // 0.8MB
    int* padprefT   = (int*)p;  p += (size_t)NCHUNK * MAXNB * 4;  // 0.8MB
    int* padtotal   = (int*)p;  p += (size_t)MAXNB * 4;
    int* binpadbase = (int*)p;  p += (size_t)(MAXNB + 1) * 4;
    uint32* table  = (uint32*)p;  p += (size_t)V * 8 * 4;         // 3.2MB
    float* selfbuf = (float*)p;   p += (size_t)V * 4 * 4;         // 1.6MB
    p = (char*)(((uintptr_t)p + 63) & ~(uintptr_t)63);
    uint2* payload = (uint2*)p;   // <= (E + 8*NCHUNK*NB)*8B ~ 25.6MB

    int gv = (V + 255) / 256;

    precompute_kernel<<<gv, 256, 0, stream>>>(x, w_self0, w_n00, w_n10,
                                              w_self11, w_n01, w_n11,
                                              table, selfbuf, V);
    count_kernel<<<nchunk, 512, 0, stream>>>(dst, cntmat, E, NB);
    padscan_kernel<<<(NB + 3) / 4, 256, 0, stream>>>(cntmat, padprefT,
                                                     padtotal, NB);
    binbase_kernel<<<1, 512, 0, stream>>>(padtotal, binpadbase, NB);
    scatter_kernel<<<nchunk, BIGT, 0, stream>>>(src, dst, angles,
                                                transporters, table,
                                                padprefT, binpadbase,
                                                payload, E, NB);
    bucket_kernel<<<NB, BIGT, 0, stream>>>(payload, cntmat, binpadbase,
                                           selfbuf, e1, e2, out, V, NB);
}

// Round 15
// 144.315 us; speedup vs baseline: 1.5273x; 1.2810x over previous
//
#include <hip/hip_runtime.h>
#include <math.h>

// EquivariantWSSHead: V=100000 vertices, E=1600000 edges, C0=C1=16.
//
// R1..R12: zero-global-atomic bucket binning; bf16 table (3.2MB) + 8B
//   payload; LDS tuple-sort so scatter reads AND writes are sequential.
//   Container crashers: ext_vector kernel params, nontemporal builtins,
//   57KB LDS + register payload arrays.
// R13 (fused): per-kernel time is real; dur_us has ~70us harness floor.
// R14: bin-major line-aligned payload -> bucket FETCH 23->11.2MB but dur
//   STILL 48.6us (260GB/s, VALU 3%). Three different bucket designs with
//   FETCH 33/23/11MB all measure 48-49us => the invariant is 6.4M
//   atomicAdd on __shared__ FLOAT — suspected CAS-loop lowering (serial
//   ~250cy/op chains, traffic-insensitive). Int LDS atomics are native
//   ds_add_u32.
// R15: bucket accumulates in FIXED-POINT INT (scale 2^17; quant err 7.6e-6
//   << bf16 payload err; |sum|*2^17 ~ 4e8 << 2^31). Also: bucket reads run
//   starts straight from padprefT (kills the 18-barrier Hillis scan).
//   Everything else identical to R14.

#define VB 256           // vertices per bucket
#define VB_SHIFT 8
#define MAXNB 400        // NB = ceil(V/256) = 391 for V=100000
#define CHUNK 3125       // edges per chunk
#define NCHUNK 512       // chunks (E/CHUNK)
#define BIGT 1024
#define FIXS 131072.0f   // 2^17 fixed-point scale
#define FIXSI (1.0f / 131072.0f)

typedef unsigned int uint32;

static __device__ __forceinline__ uint32 f2bf(float f) {
    uint32 u = __float_as_uint(f);
    return (u + 0x7FFFu + ((u >> 16) & 1u)) >> 16;   // RNE to bf16
}
static __device__ __forceinline__ uint32 pack2(float lo, float hi) {
    return f2bf(lo) | (f2bf(hi) << 16);
}
static __device__ __forceinline__ float bf_lo(uint32 u) {
    return __uint_as_float(u << 16);
}
static __device__ __forceinline__ float bf_hi(uint32 u) {
    return __uint_as_float(u & 0xFFFF0000u);
}

// K1: per-vertex dot-product table. 256 rows staged in LDS, row stride 49
// floats (odd stride -> conflict-free). All 256 threads compute.
__global__ __launch_bounds__(256)
void precompute_kernel(const float* __restrict__ x,
                       const float* __restrict__ w_self0,
                       const float* __restrict__ w_n00,
                       const float* __restrict__ w_n10,
                       const float* __restrict__ w_self11,
                       const float* __restrict__ w_n01,
                       const float* __restrict__ w_n11,
                       uint32* __restrict__ table,   // 8 u32/vertex
                       float* __restrict__ selfbuf,
                       int V) {
    __shared__ float stage[256 * 49];   // 50KB
    int v0 = blockIdx.x * 256;
    int nv = min(256, V - v0);
    if (nv <= 0) return;
    int tid = threadIdx.x;
    {
        const float4* x4 = (const float4*)(x + (size_t)v0 * 48);
        int n4 = nv * 12;
        for (int j = tid; j < n4; j += 256) {
            float4 f = x4[j];
            float* dp = stage + (j / 12) * 49 + (j % 12) * 4;
            dp[0] = f.x; dp[1] = f.y; dp[2] = f.z; dp[3] = f.w;
        }
    }
    __syncthreads();
    if (tid >= nv) return;
    int v = v0 + tid;
    const float* xr = stage + tid * 49;
    float d00 = 0.f, aw0 = 0.f, bw0 = 0.f, aw1 = 0.f, bw1 = 0.f;
    float d01a = 0.f, d01b = 0.f;
    float aP = 0.f, bP = 0.f, aQ = 0.f, bQ = 0.f;
    float aR = 0.f, bR = 0.f, aS = 0.f, bS = 0.f;
    float selfmag = 0.f, t1s = 0.f, t2s = 0.f;
#pragma unroll
    for (int i = 0; i < 16; ++i) {
        float x0 = xr[i];
        float a  = xr[16 + 2 * i];
        float b  = xr[17 + 2 * i];
        d00     += x0 * w_n00[i];
        selfmag += x0 * w_self0[i];
        d01a    += x0 * w_n01[i * 2 + 0];
        d01b    += x0 * w_n01[i * 2 + 1];
        float w0 = w_n10[i * 2 + 0], w1 = w_n10[i * 2 + 1];
        aw0 += a * w0;  bw0 += b * w0;
        aw1 += a * w1;  bw1 += b * w1;
        float p = w_n11[i * 4 + 0], q = w_n11[i * 4 + 1];
        float r = w_n11[i * 4 + 2], s = w_n11[i * 4 + 3];
        aP += a * p;  bP += b * p;
        aQ += a * q;  bQ += b * q;
        aR += a * r;  bR += b * r;
        aS += a * s;  bS += b * s;
        float sa_ = w_self11[i * 2 + 0], sb_ = w_self11[i * 2 + 1];
        t1s += a * sa_ - b * sb_;
        t2s += b * sa_ + a * sb_;
    }
    uint4 w0, w1;
    w0.x = pack2(d00, aw0);  w0.y = pack2(bw0, aw1);
    w0.z = pack2(bw1, d01a); w0.w = pack2(d01b, aP);
    w1.x = pack2(bP, aQ);    w1.y = pack2(bQ, aR);
    w1.z = pack2(bR, aS);    w1.w = pack2(bS, 0.f);
    uint4* tp = (uint4*)(table + (size_t)v * 8);
    tp[0] = w0;  tp[1] = w1;
    float* sf = selfbuf + (size_t)v * 4;
    sf[0] = selfmag; sf[1] = t1s; sf[2] = t2s; sf[3] = 0.f;
}

// K2: per-chunk histogram -> cntmat[bin][chunk] (stride NCHUNK).
__global__ __launch_bounds__(512)
void count_kernel(const int* __restrict__ dst,
                  int* __restrict__ cntmat,
                  int E, int NB) {
    __shared__ int hist[MAXNB];
    int b = blockIdx.x;
    int lo = b * CHUNK;
    int hi = min(E, lo + CHUNK);
    for (int i = threadIdx.x; i < NB; i += 512) hist[i] = 0;
    __syncthreads();
    for (int e = lo + threadIdx.x; e < hi; e += 512)
        atomicAdd(&hist[dst[e] >> VB_SHIFT], 1);
    __syncthreads();
    for (int i = threadIdx.x; i < NB; i += 512)
        cntmat[(size_t)i * NCHUNK + b] = hist[i];
}

// K3: one wave per bin. Padded (8-aligned) exclusive prefix over the 512
// chunk counts -> padprefT[chunk][bin] (stride MAXNB); padtotal[bin].
__global__ __launch_bounds__(256)
void padscan_kernel(const int* __restrict__ cntmat,
                    int* __restrict__ padprefT,
                    int* __restrict__ padtotal,
                    int NB) {
    int lane = threadIdx.x & 63;
    int wv = threadIdx.x >> 6;
    int bin = blockIdx.x * 4 + wv;
    if (bin >= NB) return;
    const int* row = cntmat + (size_t)bin * NCHUNK;
    int c[8], p[8];
#pragma unroll
    for (int j = 0; j < 8; ++j) {
        c[j] = row[lane * 8 + j];
        p[j] = (c[j] + 7) & ~7;
    }
    int e[8];
    int run = 0;
#pragma unroll
    for (int j = 0; j < 8; ++j) { e[j] = run; run += p[j]; }
    int T = run;
    int incl = T;
#pragma unroll
    for (int d = 1; d < 64; d <<= 1) {
        int n = __shfl_up(incl, d);
        if (lane >= d) incl += n;
    }
    int base = incl - T;
#pragma unroll
    for (int j = 0; j < 8; ++j)
        padprefT[(size_t)(lane * 8 + j) * MAXNB + bin] = base + e[j];
    if (lane == 63) padtotal[bin] = incl;
}

// K4: exclusive scan of padtotal -> binpadbase[0..NB].
__global__ __launch_bounds__(512)
void binbase_kernel(const int* __restrict__ padtotal,
                    int* __restrict__ binpadbase,
                    int NB) {
    __shared__ int wsum[8];
    int t = threadIdx.x;
    int lane = t & 63;
    int wv = t >> 6;
    int val = (t < NB) ? padtotal[t] : 0;
    int incl = val;
#pragma unroll
    for (int d = 1; d < 64; d <<= 1) {
        int n = __shfl_up(incl, d);
        if (lane >= d) incl += n;
    }
    if (lane == 63) wsum[wv] = incl;
    __syncthreads();
    if (t < 8) {
        int wval = wsum[t], winc = wval;
#pragma unroll
        for (int d = 1; d < 8; d <<= 1) {
            int n = __shfl_up(winc, d);
            if (lane >= d) winc += n;
        }
        wsum[t] = winc - wval;
    }
    __syncthreads();
    int ex = incl - val + wsum[wv];
    if (t < NB) binpadbase[t] = ex;
    if (t == NB - 1) binpadbase[NB] = ex + val;
}

// K5: local LDS tuple-sort + compute + write into bin-major line-aligned
// runs at binpadbase[bin] + padprefT[chunk][bin].
__global__ __launch_bounds__(BIGT)
void scatter_kernel(const int* __restrict__ src,
                    const int* __restrict__ dst,
                    const float* __restrict__ angles,
                    const float* __restrict__ transporters,
                    const uint32* __restrict__ table,
                    const int* __restrict__ padprefT,
                    const int* __restrict__ binpadbase,
                    uint2* __restrict__ payload,
                    int E, int NB) {
    __shared__ int cnt_l[MAXNB];
    __shared__ int exoff_l[MAXNB];
    __shared__ int slot_l[MAXNB];
    __shared__ int wsum[16];
    __shared__ uint32 tw_src[CHUNK];
    __shared__ uint32 tw_ang[CHUNK];
    __shared__ uint32 tw_tr[CHUNK];
    __shared__ unsigned short tw_bin[CHUNK];

    int b = blockIdx.x;
    int lo = b * CHUNK;
    int hi = min(E, lo + CHUNK);
    int nloc = hi - lo;
    int tid = threadIdx.x;
    int lane = tid & 63;
    int wv = tid >> 6;

    for (int i = tid; i < NB; i += BIGT) cnt_l[i] = 0;
    __syncthreads();

    // pass1: histogram (dst stays L1/L2-warm for pass1b)
    for (int e = lo + tid; e < hi; e += BIGT)
        atomicAdd(&cnt_l[dst[e] >> VB_SHIFT], 1);
    __syncthreads();

    // local exclusive scan over NB counts (shfl two-level)
    int c = (tid < NB) ? cnt_l[tid] : 0;
    int incl = c;
#pragma unroll
    for (int d = 1; d < 64; d <<= 1) {
        int n = __shfl_up(incl, d);
        if (lane >= d) incl += n;
    }
    if (lane == 63) wsum[wv] = incl;
    __syncthreads();
    if (tid < 16) {
        int wval = wsum[tid], winc = wval;
#pragma unroll
        for (int d = 1; d < 16; d <<= 1) {
            int n = __shfl_up(winc, d);
            if (lane >= d) winc += n;
        }
        wsum[tid] = winc - wval;
    }
    __syncthreads();
    if (tid < NB) {
        int ex = incl - c + wsum[wv];
        exoff_l[tid] = ex;
        cnt_l[tid] = ex;                         // cursor
        slot_l[tid] = binpadbase[tid] + padprefT[(size_t)b * MAXNB + tid];
    }
    __syncthreads();

    // pass1b: coalesced reads; tuple -> bin-sorted LDS slot
    for (int e = lo + tid; e < hi; e += BIGT) {
        int d = dst[e];
        int bin = d >> VB_SHIFT;
        uint32 dl = (uint32)(d & (VB - 1));
        int pos = atomicAdd(&cnt_l[bin], 1);
        tw_src[pos] = (uint32)src[e] | (dl << 17);
        tw_ang[pos] = __float_as_uint(angles[e]);
        tw_tr[pos]  = __float_as_uint(transporters[e]);
        tw_bin[pos] = (unsigned short)bin;
    }
    __syncthreads();

    // pass2: compute in bin order, write line-aligned bin-major runs
    for (int k = tid; k < nloc; k += BIGT) {
        int bin = (int)tw_bin[k];
        uint32 w0i = tw_src[k];
        int s  = (int)(w0i & 0x1FFFFu);
        int dl = (int)(w0i >> 17);
        float ang = __uint_as_float(tw_ang[k]);
        float trv = __uint_as_float(tw_tr[k]);
        float st, ct, sg, cg;
        sincosf(ang, &st, &ct);
        sincosf(trv, &sg, &cg);
        float c2t = ct * ct - st * st;
        float s2t = 2.0f * st * ct;

        const uint4* tp = (const uint4*)(table + (size_t)s * 8);
        uint4 W0 = tp[0], W1 = tp[1];
        float d00 = bf_lo(W0.x), aw0 = bf_hi(W0.x);
        float bw0 = bf_lo(W0.y), aw1 = bf_hi(W0.y);
        float bw1 = bf_lo(W0.z), d01a = bf_hi(W0.z);
        float d01b = bf_lo(W0.w), aP = bf_hi(W0.w);
        float bP = bf_lo(W1.x), aQ = bf_hi(W1.x);
        float bQ = bf_lo(W1.y), aR = bf_hi(W1.y);
        float bR = bf_lo(W1.z), aS = bf_hi(W1.z);
        float bS = bf_lo(W1.w);

        float u1w0 = cg * aw0 - sg * bw0, u2w0 = sg * aw0 + cg * bw0;
        float u1w1 = cg * aw1 - sg * bw1, u2w1 = sg * aw1 + cg * bw1;
        float m0 = d00 + ct * u1w0 + st * u2w0 - st * u1w1 + ct * u2w1;

        float u1p = cg * aP - sg * bP, u2p = sg * aP + cg * bP;
        float u1q = cg * aQ - sg * bQ, u2q = sg * aQ + cg * bQ;
        float u1r = cg * aR - sg * bR, u2r = sg * aR + cg * bR;
        float u1s = cg * aS - sg * bS, u2s = sg * aS + cg * bS;

        float mv1 = d01a * ct - d01b * st
                  + u1p - u2q
                  + c2t * u1r + s2t * u2r
                  - (s2t * u1s - c2t * u2s);
        float mv2 = d01a * st + d01b * ct
                  + u2p + u1q
                  + s2t * u1r - c2t * u2r
                  + c2t * u1s + s2t * u2s;

        uint2 pl;
        pl.x = pack2(m0, mv1);
        pl.y = f2bf(mv2) | ((uint32)dl << 16);
        payload[slot_l[bin] + (k - exoff_l[bin])] = pl;
    }
}

// K6: one block per bin. Contiguous stream read of the bin's padded region;
// run starts read straight from padprefT (no scan); INT fixed-point LDS
// accumulate (native ds_add_u32, no fp-atomic CAS path); fused finalize.
__global__ __launch_bounds__(BIGT)
void bucket_kernel(const uint2* __restrict__ payload,
                   const int* __restrict__ cntmat,
                   const int* __restrict__ padprefT,
                   const int* __restrict__ binpadbase,
                   const float* __restrict__ selfbuf,
                   const float* __restrict__ e1,
                   const float* __restrict__ e2,
                   float* __restrict__ out,
                   int V, int NB) {
    __shared__ int iacc[8][VB * 4];      // 32KB, wave w uses copy w>>1
    __shared__ int len_l[NCHUNK];
    __shared__ int pstart_l[NCHUNK];
    __shared__ unsigned short group2run[2048];
    int bin = blockIdx.x;
    int tid = threadIdx.x;
    for (int i = tid; i < 8 * VB * 4; i += BIGT) ((int*)iacc)[i] = 0;

    if (tid < NCHUNK) {
        int len = cntmat[(size_t)bin * NCHUNK + tid];
        int ps  = padprefT[(size_t)tid * MAXNB + bin];
        len_l[tid] = len;
        pstart_l[tid] = ps;
        int g0 = ps >> 3, gn = (len + 7) >> 3;
        for (int j = 0; j < gn; ++j)
            group2run[g0 + j] = (unsigned short)tid;
    }
    __syncthreads();

    int base = binpadbase[bin];
    int ptot = binpadbase[bin + 1] - base;
    int* myacc = iacc[tid >> 7];
    for (int k = tid; k < ptot; k += BIGT) {
        int r = (int)group2run[k >> 3];
        int local = k - pstart_l[r];
        if (local < len_l[r]) {
            uint2 pl = payload[base + k];
            float m0  = bf_lo(pl.x);
            float mv1 = bf_hi(pl.x);
            float mv2 = bf_lo(pl.y);
            int dl = (int)(pl.y >> 16);
            atomicAdd(&myacc[dl * 4 + 0], __float2int_rn(m0 * FIXS));
            atomicAdd(&myacc[dl * 4 + 1], __float2int_rn(mv1 * FIXS));
            atomicAdd(&myacc[dl * 4 + 2], __float2int_rn(mv2 * FIXS));
            atomicAdd(&myacc[dl * 4 + 3], 1);
        }
    }
    __syncthreads();
    if (tid < VB) {
        int v = bin * VB + tid;
        if (v < V) {
            int I0 = 0, I1 = 0, I2 = 0, I3 = 0;
#pragma unroll
            for (int w = 0; w < 8; ++w) {
                I0 += iacc[w][tid * 4 + 0];
                I1 += iacc[w][tid * 4 + 1];
                I2 += iacc[w][tid * 4 + 2];
                I3 += iacc[w][tid * 4 + 3];
            }
            float A0 = (float)I0 * FIXSI;
            float A1 = (float)I1 * FIXSI;
            float A2 = (float)I2 * FIXSI;
            float inv = 1.0f / fmaxf((float)I3, 1.0f);
            const float* sf = selfbuf + (size_t)v * 4;
            float mag = A0 * inv + sf[0];
            float t1  = A1 * inv + sf[1];
            float t2  = A2 * inv + sf[2];
            float scale = 2.0f / (1.0f + expf(-mag));
            float e1x = e1[v * 3 + 0], e1y = e1[v * 3 + 1], e1z = e1[v * 3 + 2];
            float e2x = e2[v * 3 + 0], e2y = e2[v * 3 + 1], e2z = e2[v * 3 + 2];
            out[v * 3 + 0] = (t1 * e1x + t2 * e2x) * scale;
            out[v * 3 + 1] = (t1 * e1y + t2 * e2y) * scale;
            out[v * 3 + 2] = (t1 * e1z + t2 * e2z) * scale;
        }
    }
}

extern "C" void kernel_launch(void* const* d_in, const int* in_sizes, int n_in,
                              void* d_out, int out_size, void* d_ws, size_t ws_size,
                              hipStream_t stream) {
    const float* x            = (const float*)d_in[0];
    const int*   edge_index   = (const int*)d_in[1];
    const float* angles       = (const float*)d_in[2];
    const float* transporters = (const float*)d_in[3];
    const float* e1           = (const float*)d_in[4];
    const float* e2           = (const float*)d_in[5];
    const float* w_self0      = (const float*)d_in[6];
    const float* w_n00        = (const float*)d_in[7];
    const float* w_n10        = (const float*)d_in[8];
    const float* w_self11     = (const float*)d_in[9];
    const float* w_n01        = (const float*)d_in[10];
    const float* w_n11        = (const float*)d_in[11];
    float* out = (float*)d_out;

    int V = in_sizes[0] / 48;
    int E = in_sizes[2];
    const int* src = edge_index;
    const int* dst = edge_index + E;

    int NB = (V + VB - 1) / VB;              // 391
    int nchunk = (E + CHUNK - 1) / CHUNK;    // 512

    char* p = (char*)d_ws;
    int* cntmat     = (int*)p;  p += (size_t)MAXNB * NCHUNK * 4;  // 0.8MB
    int* padprefT   = (int*)p;  p += (size_t)NCHUNK * MAXNB * 4;  // 0.8MB
    int* padtotal   = (int*)p;  p += (size_t)MAXNB * 4;
    int* binpadbase = (int*)p;  p += (size_t)(MAXNB + 1) * 4;
    uint32* table  = (uint32*)p;  p += (size_t)V * 8 * 4;         // 3.2MB
    float* selfbuf = (float*)p;   p += (size_t)V * 4 * 4;         // 1.6MB
    p = (char*)(((uintptr_t)p + 63) & ~(uintptr_t)63);
    uint2* payload = (uint2*)p;   // <= (E + 8*NCHUNK*NB)*8B ~ 25.6MB

    int gv = (V + 255) / 256;

    precompute_kernel<<<gv, 256, 0, stream>>>(x, w_self0, w_n00, w_n10,
                                              w_self11, w_n01, w_n11,
                                              table, selfbuf, V);
    count_kernel<<<nchunk, 512, 0, stream>>>(dst, cntmat, E, NB);
    padscan_kernel<<<(NB + 3) / 4, 256, 0, stream>>>(cntmat, padprefT,
                                                     padtotal, NB);
    binbase_kernel<<<1, 512, 0, stream>>>(padtotal, binpadbase, NB);
    scatter_kernel<<<nchunk, BIGT, 0, stream>>>(src, dst, angles,
                                                transporters, table,
                                                padprefT, binpadbase,
                                                payload, E, NB);
    bucket_kernel<<<NB, BIGT, 0, stream>>>(payload, cntmat, padprefT,
                                           binpadbase, selfbuf,
                                           e1, e2, out, V, NB);
}